// Round 15
// baseline (130.722 us; speedup 1.0000x reference)
//
#include <hip/hip_runtime.h>
#include <math.h>

// Chamfer distance via EXACT grid nearest-neighbor (fp32, no quantization).
//
// R24 vs R23: R23's null (40.6us query, Occ 25%) isolates the cost to the
// serial dependent-load paths (rings + fallback scan_cell) that put a long
// tail in SOME blocks -- staging the average was never the problem. This
// round removes EVERY chain from the query kernel: box-only staged eval
// (exact iff best <= h^2: outside the 3x3x3 box every point is >= h away);
// everything else -- unconverged, straddle, union-too-big -- goes to a
// worklist handled by a slab-brute kernel (contiguous z-slab [cz+-5] span,
// one lookup + pure L2 streaming; exact iff best <= (5h)^2, else stream the
// rest; ~220 items expected by the Poisson model anchored at R22's
// measurement). G 48->32 (h=0.4125) improves the box threshold AND shrinks
// bookkeeping (64 scan blocks); scan2 folded into scan3 (bsums = 64 = one
// wave-scan). 7 dispatches, no grid.sync, clamped binning min-safe (R20).

typedef unsigned int uint;

constexpr int   G    = 32;
constexpr int   G3   = G * G * G;          // 32768 cells per cloud
constexpr float FLO  = -6.6f;
constexpr float FH   = 13.2f / (float)G;   // 0.4125
constexpr float FINVH = (float)G / 13.2f;

constexpr int CAP   = 4096;                // staged candidate cap (SoA 48 KB)
constexpr int NRMAX = 64;                  // staged row cap (one wave computes)
constexpr int RSLAB = 5;                   // brute slab half-width (5h = 2.06)

__device__ __forceinline__ int cell1(float x) {
    int c = (int)((x - FLO) * FINVH);
    return c < 0 ? 0 : (c > G - 1 ? G - 1 : c);
}

// ---- 1: histogram of cell occupancy (both clouds, concatenated) ----
__global__ __launch_bounds__(256) void hist_kernel(
    const float* __restrict__ P1, const float* __restrict__ P2,
    uint* __restrict__ counts, int n1, int n2)
{
    int i = blockIdx.x * 256 + threadIdx.x;
    const float* P; int base, j;
    if (i < n1)            { P = P1; base = 0;  j = i; }
    else if (i < n1 + n2)  { P = P2; base = G3; j = i - n1; }
    else return;
    float x = P[3*j], y = P[3*j+1], z = P[3*j+2];
    int lin = (cell1(z) * G + cell1(y)) * G + cell1(x);
    atomicAdd(&counts[base + lin], 1u);
}

// ---- 2: block exclusive scan, wave-shuffle (64 blocks x 1024) ----
__global__ __launch_bounds__(1024) void scan1_kernel(
    const uint* __restrict__ counts, uint* __restrict__ starts,
    uint* __restrict__ bsums)
{
    __shared__ uint ws[16];
    int gid = blockIdx.x * 1024 + threadIdx.x;
    int lane = threadIdx.x & 63, w = threadIdx.x >> 6;
    uint v = counts[gid];
    uint x = v;                                   // inclusive wave scan
#pragma unroll
    for (int d = 1; d < 64; d <<= 1) { uint t = __shfl_up(x, d); if (lane >= d) x += t; }
    if (lane == 63) ws[w] = x;
    __syncthreads();
    if (w == 0) {
        uint y = (lane < 16) ? ws[lane] : 0u;
#pragma unroll
        for (int d = 1; d < 16; d <<= 1) { uint t = __shfl_up(y, d); if (lane >= d) y += t; }
        if (lane < 16) ws[lane] = y;
    }
    __syncthreads();
    uint add = (w > 0) ? ws[w - 1] : 0u;
    starts[gid] = add + x - v;                    // exclusive (block-local)
    if (threadIdx.x == 1023) bsums[blockIdx.x] = add + x;
}

// ---- 3: finalize scan (bsums = 64 values: wave-scan per block), cursor copy ----
__global__ __launch_bounds__(1024) void scan23_kernel(
    uint* __restrict__ starts, uint* __restrict__ cursor,
    const uint* __restrict__ bsums, float* __restrict__ out,
    uint* __restrict__ wlcount)
{
    __shared__ uint ws[64];
    int tid = threadIdx.x;
    if (tid < 64) {
        uint x = bsums[tid];                      // inclusive 64-lane scan
#pragma unroll
        for (int d = 1; d < 64; d <<= 1) { uint t = __shfl_up(x, d); if (tid >= d) x += t; }
        ws[tid] = x;
    }
    __syncthreads();
    uint add = (blockIdx.x > 0) ? ws[blockIdx.x - 1] : 0u;
    int gid = blockIdx.x * 1024 + tid;
    uint v = starts[gid] + add;
    starts[gid] = v;
    cursor[gid] = v;
    if (gid == 0) { out[0] = 0.0f; wlcount[0] = 0u; }   // before query atomics
}

// ---- 4: scatter points into cell-ordered slots ----
__global__ __launch_bounds__(256) void scatter_kernel(
    const float* __restrict__ P1, const float* __restrict__ P2,
    uint* __restrict__ cursor, float4* __restrict__ scat, int n1, int n2)
{
    int i = blockIdx.x * 256 + threadIdx.x;
    const float* P; int base, j;
    if (i < n1)            { P = P1; base = 0;  j = i; }
    else if (i < n1 + n2)  { P = P2; base = G3; j = i - n1; }
    else return;
    float x = P[3*j], y = P[3*j+1], z = P[3*j+2];
    int lin = (cell1(z) * G + cell1(y)) * G + cell1(x);
    uint pos = atomicAdd(&cursor[base + lin], 1u);
    scat[pos] = make_float4(x, y, z, 0.0f);
}

// ---- 5: query. Block = 16 queries; staged union-box eval ONLY.
//         Unconverged / fallback blocks -> worklist. Zero dependent chains. ----
__global__ __launch_bounds__(256) void query_kernel(
    const uint* __restrict__ starts, const float4* __restrict__ scat,
    float* __restrict__ out, uint* __restrict__ wl, uint* __restrict__ wlcount,
    int n1, int n2)
{
    __shared__ float sx[CAP], sy[CAP], sz[CAP];
    __shared__ uint  rOff[NRMAX];       // global span start per staged row
    __shared__ uint  rCum[NRMAX + 1];   // exclusive cumulative staged offsets
    __shared__ int   qc[16][3];
    __shared__ int   sInfo[8];          // X0,X1,Y0,YR,Z0,NR,fbflag,total
    __shared__ float red[4];

    const int nTot  = n1 + n2;          // 32768; % 16 == 0 -> all blocks full
    const int tid   = threadIdx.x;
    const int sub   = tid & 15;
    const int grp   = tid >> 4;
    const int qbase = blockIdx.x * 16;
    const int i     = qbase + grp;

    const int  cb       = (qbase < n1) ? G3 : 0;             // other cloud
    const bool straddle = ((qbase < n1) != (qbase + 15 < n1));

    // ---- union of the 16 query cells (+1 ring), block-shared ----
    if (tid < 16) {
        float4 q = scat[qbase + tid];
        qc[tid][0] = cell1(q.x); qc[tid][1] = cell1(q.y); qc[tid][2] = cell1(q.z);
    }
    __syncthreads();
    if (tid == 0) {
        int x0 = qc[0][0], x1 = x0, y0 = qc[0][1], y1 = y0, z0 = qc[0][2], z1 = z0;
        for (int j = 1; j < 16; ++j) {
            int a = qc[j][0], b = qc[j][1], c = qc[j][2];
            x0 = a < x0 ? a : x0;  x1 = a > x1 ? a : x1;
            y0 = b < y0 ? b : y0;  y1 = b > y1 ? b : y1;
            z0 = c < z0 ? c : z0;  z1 = c > z1 ? c : z1;
        }
        x0 = x0 > 0 ? x0 - 1 : 0;  x1 = x1 < G - 1 ? x1 + 1 : G - 1;
        y0 = y0 > 0 ? y0 - 1 : 0;  y1 = y1 < G - 1 ? y1 + 1 : G - 1;
        z0 = z0 > 0 ? z0 - 1 : 0;  z1 = z1 < G - 1 ? z1 + 1 : G - 1;
        int yr = y1 - y0 + 1, nr = (z1 - z0 + 1) * yr;
        sInfo[0] = x0; sInfo[1] = x1; sInfo[2] = y0; sInfo[3] = yr; sInfo[4] = z0;
        sInfo[5] = nr;
        sInfo[6] = (straddle || nr > NRMAX) ? 1 : 0;
        sInfo[7] = 0;
    }
    __syncthreads();

    const int NR = sInfo[5];
    bool fb = sInfo[6] != 0;

    // ---- row spans (contiguous CSR runs) + wave-0 prefix scan ----
    if (!fb && tid < 64) {
        uint len = 0;
        if (tid < NR) {
            int z = sInfo[4] + tid / sInfo[3];
            int y = sInfo[2] + tid % sInfo[3];
            int rowb = cb + (z * G + y) * G;
            int gi1  = rowb + sInfo[1] + 1;
            uint s = starts[rowb + sInfo[0]];
            uint e = (gi1 < 2 * G3) ? starts[gi1] : (uint)nTot;
            rOff[tid] = s;
            len = e - s;
        }
        uint x = len;
#pragma unroll
        for (int d = 1; d < 64; d <<= 1) { uint t = __shfl_up(x, d); if (tid >= d) x += t; }
        rCum[tid + 1] = x;
        if (tid == 0)  rCum[0] = 0;
        if (tid == 63) sInfo[7] = (int)x;      // total (lanes >= NR added zeros)
    }
    __syncthreads();

    const int total = sInfo[7];
    fb = fb || (total > CAP);                  // block-uniform

    // ---- cooperative staged copy (SoA; binary search row by offset) ----
    if (!fb) {
        for (int c = tid; c < total; c += 256) {
            int lo = 0, hi = NR - 1;
            while (lo < hi) { int mid = (lo + hi + 1) >> 1; if ((int)rCum[mid] <= c) lo = mid; else hi = mid - 1; }
            float4 p = scat[rOff[lo] + (uint)(c - (int)rCum[lo])];
            sx[c] = p.x; sy[c] = p.y; sz[c] = p.z;
        }
    }
    __syncthreads();

    // ---- per-query eval: staged candidates only (covers the full 3x3x3 box;
    //      extra candidates only lower best -- safe) ----
    float acc = 0.0f;
    {
        float4 q = scat[i];
        float best = 1e30f;
        if (!fb) {
            for (int c = sub; c < total; c += 16) {
                float dx = q.x - sx[c], dy = q.y - sy[c], dz = q.z - sz[c];
                best = fminf(best, dx*dx + dy*dy + dz*dz);
            }
#pragma unroll
            for (int m = 1; m <= 8; m <<= 1) best = fminf(best, __shfl_xor(best, m, 16));
        }
        // exact iff best <= h^2 (everything outside the box is >= h away)
        if (!fb && best <= FH * FH) {
            if (sub == 0) acc = sqrtf(best);
        } else {
            if (sub == 0) { uint pos = atomicAdd(wlcount, 1u); wl[pos] = (uint)i; }
        }
    }

    // block sum: sub==0 lanes live at wave lanes 0,16,32,48
#pragma unroll
    for (int m = 16; m <= 32; m <<= 1) acc += __shfl_xor(acc, m);
    if ((tid & 63) == 0) red[tid >> 6] = acc;
    __syncthreads();
    if (tid == 0) atomicAdd(out, red[0] + red[1] + red[2] + red[3]);
}

// ---- 6: slab-brute the worklist: one block per item; contiguous z-slab span
//         (one lookup -> pure streaming); rare full-range continuation ----
__global__ __launch_bounds__(256) void brute_kernel(
    const uint* __restrict__ starts, const float4* __restrict__ scat,
    const uint* __restrict__ wl, const uint* __restrict__ wlcount,
    float* __restrict__ out, int n1, int n2)
{
    __shared__ float red[4];
    __shared__ float sbest;
    const int nTot = n1 + n2;
    const uint cnt = wlcount[0];
    for (uint w = blockIdx.x; w < cnt; w += gridDim.x) {
        uint qi = wl[w];
        float4 q = scat[qi];
        const int cb = (qi < (uint)n1) ? G3 : 0;       // other cloud cells
        const uint ob = (qi < (uint)n1) ? (uint)n1 : 0u;
        const uint oe = (qi < (uint)n1) ? (uint)nTot : (uint)n1;

        int cz = cell1(q.z);
        int z0 = cz - RSLAB > 0 ? cz - RSLAB : 0;
        int z1 = cz + RSLAB < G - 1 ? cz + RSLAB : G - 1;
        int gi1 = cb + (z1 + 1) * G * G;
        uint ss = starts[cb + z0 * G * G];
        uint se = (gi1 < 2 * G3) ? starts[gi1] : (uint)nTot;

        float best = 1e30f;
        for (uint j = ss + threadIdx.x; j < se; j += 256) {
            float4 p = scat[j];
            float dx = q.x - p.x, dy = q.y - p.y, dz = q.z - p.z;
            best = fminf(best, dx*dx + dy*dy + dz*dz);
        }
#pragma unroll
        for (int m = 1; m <= 32; m <<= 1) best = fminf(best, __shfl_xor(best, m));
        if ((threadIdx.x & 63) == 0) red[threadIdx.x >> 6] = best;
        __syncthreads();
        if (threadIdx.x == 0)
            sbest = fminf(fminf(red[0], red[1]), fminf(red[2], red[3]));
        __syncthreads();
        float b = sbest;

        // slab bound: outside [cz-R, cz+R], |qz-pz| >= R*h
        const float thr = (float)RSLAB * FH * (float)RSLAB * FH;
        if (b > thr) {                               // rare (~handful of items)
            best = b;
            for (uint j = ob + threadIdx.x; j < ss; j += 256) {
                float4 p = scat[j];
                float dx = q.x - p.x, dy = q.y - p.y, dz = q.z - p.z;
                best = fminf(best, dx*dx + dy*dy + dz*dz);
            }
            for (uint j = se + threadIdx.x; j < oe; j += 256) {
                float4 p = scat[j];
                float dx = q.x - p.x, dy = q.y - p.y, dz = q.z - p.z;
                best = fminf(best, dx*dx + dy*dy + dz*dz);
            }
#pragma unroll
            for (int m = 1; m <= 32; m <<= 1) best = fminf(best, __shfl_xor(best, m));
            if ((threadIdx.x & 63) == 0) red[threadIdx.x >> 6] = best;
            __syncthreads();
            if (threadIdx.x == 0)
                sbest = fminf(fminf(red[0], red[1]), fminf(red[2], red[3]));
            __syncthreads();
            b = sbest;
        }

        if (threadIdx.x == 0) atomicAdd(out, sqrtf(b));
        __syncthreads();                             // red/sbest reused next item
    }
}

extern "C" void kernel_launch(void* const* d_in, const int* in_sizes, int n_in,
                              void* d_out, int out_size, void* d_ws, size_t ws_size,
                              hipStream_t stream) {
    const float* P1 = (const float*)d_in[0];
    const float* P2 = (const float*)d_in[1];
    const int n1 = in_sizes[0] / 3;   // 16384
    const int n2 = in_sizes[1] / 3;   // 16384
    const int nTot = n1 + n2;
    const int NB = (2 * G3) / 1024;   // 64 scan blocks

    uint*   counts  = (uint*)d_ws;                // [65536]
    uint*   starts  = counts + 2 * G3;            // [65536]
    uint*   cursor  = starts + 2 * G3;            // [65536]
    uint*   bsums   = cursor + 2 * G3;            // [64], padded to 256
    float4* scat    = (float4*)(bsums + 256);     // 16B-aligned by layout
    uint*   wl      = (uint*)(scat + 32768);
    uint*   wlcount = wl + 32768;
    float*  out     = (float*)d_out;

    hipMemsetAsync(counts, 0, 2 * G3 * sizeof(uint), stream);

    hist_kernel   <<<(nTot + 255) / 256, 256, 0, stream>>>(P1, P2, counts, n1, n2);
    scan1_kernel  <<<NB, 1024, 0, stream>>>(counts, starts, bsums);
    scan23_kernel <<<NB, 1024, 0, stream>>>(starts, cursor, bsums, out, wlcount);
    scatter_kernel<<<(nTot + 255) / 256, 256, 0, stream>>>(P1, P2, cursor, scat, n1, n2);
    query_kernel  <<<nTot / 16, 256, 0, stream>>>(starts, scat, out, wl, wlcount, n1, n2);
    brute_kernel  <<<512, 256, 0, stream>>>(starts, scat, wl, wlcount, out, n1, n2);
}

// Round 16
// 92.455 us; speedup vs baseline: 1.4139x; 1.4139x over previous
//
#include <hip/hip_runtime.h>
#include <math.h>

// Chamfer distance via MFMA, fp16 quantized / fp32 accumulate.
// K-packing: A_row = (-2ax,-2ay,-2az, 1, sqa, 0,0,0), B_col = (bx,by,bz, sqb, 1, 0,0,0)
// => MFMA dot = sqa + sqb - 2 a.b = full squared distance (from quantized coords).
//
// R25 = DIAGNOSTIC on R13 (proven 78.1us): the sweep loop runs the B cloud
// TWICE (second pass rotated one tile; min is idempotent -> identical
// result). Rationale: every kernel this session (MFMA sweeps, grid queries)
// measures 4-8x above its issue/latency model, and 12 structurally
// different optimizations were null -- the error is in a SHARED assumption.
// This run splits the ~28us kernel into sweep-issue cost (doubles) vs
// fixed/clock overhead (doesn't):
//   dur ~78  -> sweep <=3us, ~25us fixed overhead (attack overhead next)
//   dur ~84  -> sweep ~6us = issue model OK, rest overhead
//   dur >100 -> sweep is the full cost: real issue/clock wall -> R13 is
//               the practical floor; restore it and stop.
// Everything else is byte-identical to R13: 2 dispatches (memset4B + fused
// kernel), full B cloud packed in-kernel to 128KB LDS, BLK=1024 = 16 waves
// = 4/SIMD, waves = 4 row-groups x 4 B-quarters, no grid.sync.

typedef _Float16 half8    __attribute__((ext_vector_type(8)));
typedef float    floatx16 __attribute__((ext_vector_type(16)));

constexpr int NPTS = 16384;    // padded cloud size (128 KB LDS), fixed problem
constexpr int ROWS = 128;      // A-rows per block (4 row-groups * 32)
constexpr int BLK  = 1024;     // 16 waves = 4/SIMD at 1 block/CU

// ---- pack one point into an f16 fragment (x,y,z,|p|^2) ----
__device__ __forceinline__ uint2 pack_point(const float* __restrict__ P, int j)
{
    float x = P[3*j], y = P[3*j+1], z = P[3*j+2];
    _Float16 hx = (_Float16)x, hy = (_Float16)y, hz = (_Float16)z;
    float qx = (float)hx, qy = (float)hy, qz = (float)hz;
    _Float16 hw = (_Float16)(qx*qx + qy*qy + qz*qz);
    union { _Float16 h[4]; uint2 u; } p;
    p.h[0] = hx; p.h[1] = hy; p.h[2] = hz; p.h[3] = hw;
    return p.u;
}

// One fused kernel: pack B->LDS, pack own A-rows->regs, sweep x2, reduce, atomicAdd.
__global__ __launch_bounds__(BLK, 4) void chamfer_all_kernel(
    const float* __restrict__ P1, const float* __restrict__ P2,
    float* __restrict__ out, int n1, int n2)
{
    __shared__ uint2 sB[NPTS];            // packed B cloud
    __shared__ float sRowMin[4][ROWS];    // per-B-quarter row mins
    __shared__ float sRed[ROWS];          // final per-row sqrt'd values

    const int dir   = blockIdx.z;
    const float* PA = dir == 0 ? P1 : P2;
    const float* PB = dir == 0 ? P2 : P1;
    const int nA    = dir == 0 ? n1 : n2;
    const int nB    = dir == 0 ? n2 : n1;

    const int tid  = threadIdx.x;
    const int wave = tid >> 6;
    const int lane = tid & 63;
    const int n    = lane & 31;
    const int g    = lane >> 5;
    const bool g0  = (g == 0);
    const int wr   = wave & 3;        // row-group: rows wr*32 .. wr*32+31
    const int wq   = wave >> 2;       // B-quarter index

    // ---- pack the FULL B cloud into LDS (reads are L2-resident, 192 KB) ----
    for (int j = tid; j < NPTS; j += BLK) {
        int jj = j < nB ? j : nB - 1;        // pad with dup of last point
        sB[j] = pack_point(PB, jj);
    }

    // ---- A fragment: pack own row directly from fp32 points ----
    const _Float16 h0 = (_Float16)0.0f;
    half8 af;
    {
        int arow = blockIdx.x * ROWS + wr * 32 + n;
        int j = arow < nA ? arow : nA - 1;
        union { uint2 u; _Float16 h[4]; } au; au.u = pack_point(PA, j);
        const _Float16 m2 = (_Float16)(-2.0f);
        af[0] = g0 ? (_Float16)(au.h[0] * m2) : h0;
        af[1] = g0 ? (_Float16)(au.h[1] * m2) : h0;
        af[2] = g0 ? (_Float16)(au.h[2] * m2) : h0;
        af[3] = g0 ? (_Float16)1.0f : h0;
        af[4] = g0 ? au.h[3] : h0;
        af[5] = h0; af[6] = h0; af[7] = h0;
    }

    __syncthreads();

    floatx16 rowmin;
#pragma unroll
    for (int r = 0; r < 16; ++r) rowmin[r] = 1e30f;
    const floatx16 zacc = {};

    // Persistent B-operand quads: upper pair (1.0h,0 | 0,0) written ONCE;
    // per-step the prefetched uint2 lands in the lower pair.
    union BF { half8 v; unsigned u[4]; uint2 lo; };
    BF bu0, bu1;
    { union { _Float16 h[2]; unsigned u; } q;
      q.h[0] = (_Float16)1.0f; q.h[1] = h0;
      bu0.u[2] = q.u; bu0.u[3] = 0u;
      bu1.u[2] = q.u; bu1.u[3] = 0u; }

    // ---- sweep own B-quarter TWICE: 2*64 steps (second pass rotated by one
    //      tile -> same candidate set, min-idempotent, no compiler dedup) ----
    constexpr int QLEN = NPTS >> 2;            // 4096
    constexpr int NT   = QLEN / 64;            // 64 steps per pass
    const uint2* qbase = sB + wq * QLEN + n;   // g0/g1 broadcast same addr
    uint2 c0 = qbase[0], c1 = qbase[32];

    for (int bt2 = 0; bt2 < 2 * NT; ++bt2) {
        const uint2* pn = qbase + ((bt2 + 1) & (NT - 1)) * 64;
        uint2 f0 = pn[0], f1 = pn[32];

        bu0.lo = c0;
        bu1.lo = c1;

        floatx16 d0 = __builtin_amdgcn_mfma_f32_32x32x16_f16(af, bu0.v, zacc, 0, 0, 0);
        floatx16 d1 = __builtin_amdgcn_mfma_f32_32x32x16_f16(af, bu1.v, zacc, 0, 0, 0);

#pragma unroll
        for (int r = 0; r < 16; ++r)
            rowmin[r] = fminf(fminf(rowmin[r], d0[r]), d1[r]);   // v_min3

        c0 = f0; c1 = f1;
    }

    // ---- reduce across the 32 cols (xor-shuffle within n-group) ----
#pragma unroll
    for (int mask = 1; mask <= 16; mask <<= 1)
#pragma unroll
        for (int r = 0; r < 16; ++r)
            rowmin[r] = fminf(rowmin[r], __shfl_xor(rowmin[r], mask));

    if (n == 0) {
#pragma unroll
        for (int r = 0; r < 16; ++r) {
            int rr = wr * 32 + g * 4 + ((r & 3) + 8 * (r >> 2));   // C/D row map
            sRowMin[wq][rr] = rowmin[r];
        }
    }
    __syncthreads();

    // ---- combine quarters, sqrt, block-sum, one atomicAdd ----
    if (tid < ROWS) {
        float m = fminf(fminf(sRowMin[0][tid], sRowMin[1][tid]),
                        fminf(sRowMin[2][tid], sRowMin[3][tid]));
        int grow = blockIdx.x * ROWS + tid;
        sRed[tid] = (grow < nA) ? sqrtf(fmaxf(m, 0.0f)) : 0.0f;
    }
    __syncthreads();

    if (tid < 64) {
        float v = sRed[tid] + sRed[tid + 64];
#pragma unroll
        for (int mask = 1; mask <= 32; mask <<= 1)
            v += __shfl_xor(v, mask);
        if (tid == 0) atomicAdd(out, v);
    }
}

extern "C" void kernel_launch(void* const* d_in, const int* in_sizes, int n_in,
                              void* d_out, int out_size, void* d_ws, size_t ws_size,
                              hipStream_t stream) {
    const float* P1 = (const float*)d_in[0];
    const float* P2 = (const float*)d_in[1];
    const int n1 = in_sizes[0] / 3;   // 16384
    const int n2 = in_sizes[1] / 3;   // 16384
    float* out = (float*)d_out;

    hipMemsetAsync(out, 0, sizeof(float), stream);   // capture-safe

    dim3 grid(NPTS / ROWS, 1, 2);                    // 256 blocks = exactly 1/CU
    chamfer_all_kernel<<<grid, BLK, 0, stream>>>(P1, P2, out, n1, n2);
}